// Round 8
// baseline (3095.931 us; speedup 1.0000x reference)
//
#include <hip/hip_runtime.h>

using bf = unsigned short;
typedef __attribute__((ext_vector_type(8))) short short8v;
typedef __attribute__((ext_vector_type(4))) float f32x4;
typedef __attribute__((ext_vector_type(4))) unsigned int u32x4;
typedef __attribute__((ext_vector_type(2))) unsigned int u32x2;

__device__ __forceinline__ float bf2f(bf u) { return __uint_as_float(((unsigned)u) << 16); }
__device__ __forceinline__ bf f2bf(float f) {
    unsigned x = __float_as_uint(f);
    x += 0x7fffu + ((x >> 16) & 1u);   // RNE
    return (bf)(x >> 16);
}

// async global->LDS, 16B per lane. LDS dest linear in lane id; global src per-lane.
__device__ __forceinline__ void gload16(const bf* g, bf* l) {
    __builtin_amdgcn_global_load_lds(
        (const __attribute__((address_space(1))) void*)g,
        (__attribute__((address_space(3))) void*)l, 16, 0, 0);
}

// ---------------------------------------------------------------------------
// Implicit-GEMM conv, NHWC bf16, fp32 accum. 256 thr = 4 waves (2co x 2px).
// CC=32 K-chunks, DOUBLE-buffered LDS with latency-hiding order per chunk:
//   wload(ch)->regs  [issued BEFORE next staging => weight waits don't drain it]
//   stage(ch+1)->buf^1 via global_load_lds   [in flight through compute]
//   compute(ch)      [72 MFMA + ds_reads hide staging latency]
//   __syncthreads()  [drain lands after compute - nearly free]
// Staging padded to NITER*256 granules (branchless zpage src) so every thread
// issues identical load counts. XOR swizzle on src granule + LDS read granule.
// RS==1: LDS-free direct loads. CMB==2: in-place residual combine; masked
// blocks return with zero traffic.
// ---------------------------------------------------------------------------
template <int CI, int CC, int RS, int STRIDE, bool RELU, int CMB, int TH, int TW, int W>
__global__ __launch_bounds__(256, 3) void conv_mfma(
    const bf* __restrict__ X, const bf* __restrict__ Wp,
    const float* __restrict__ bias, bf* __restrict__ Y,
    const bf* __restrict__ res, const float* __restrict__ probs,
    const bf* __restrict__ zpage, int kidx, int Co) {
    constexpr int PAD = (RS == 3) ? 1 : 0;
    constexpr int IN_ROWS = (TH - 1) * STRIDE + RS;
    constexpr int IN_COLS = (TW - 1) * STRIDE + RS;
    constexpr int NG = CC / 8;
    constexpr int HIN = W * STRIDE;
    constexpr int RSRS = RS * RS;
    constexpr int NCH = CI / CC;
    constexpr bool DIRECT = (RS == 1);
    constexpr int TG = IN_ROWS * IN_COLS * NG;
    constexpr int NITER = (TG + 255) / 256;
    constexpr int TGP = NITER * 256;           // padded granules per buffer
    constexpr int BUFE = TGP * 8;              // bf elements per buffer
    constexpr int NPX = TH * TW;
    constexpr int NF = NPX / 32;
    constexpr int TPR = W / TW;
    constexpr int KSH = (STRIDE == 2) ? 1 : 0;
    constexpr bool PIPE = (!DIRECT) && (CC == 32) && (NCH > 1);

    __shared__ bf sX[DIRECT ? 8 : (PIPE ? 2 * BUFE : BUFE)];

    const int tid = threadIdx.x;
    const int n = blockIdx.z;
    const int coBase = blockIdx.y << 6;
    const int bx = blockIdx.x;
    const int tr0 = (bx / TPR) * TH;
    const int tc0 = (bx % TPR) * TW;

    bool active = true;
    if (kidx >= 0) active = (probs[n * 15 + kidx] >= 0.5f);
    if (!active) return;   // CMB==2: Y==res in-place, already correct.

    const int lane = tid & 63;
    const int wid = tid >> 6;
    const int l15 = lane & 15;
    const int lq = lane >> 4;
    const int wm = wid >> 1;
    const int wn = wid & 1;

    f32x4 acc[2][NF] = {};
    int prow[NF], pcol[NF];
#pragma unroll
    for (int nf = 0; nf < NF; ++nf) {
        int p = wn * (NPX / 2) + nf * 16 + l15;
        prow[nf] = p / TW;
        pcol[nf] = p % TW;
    }

    const bf* Xn = X + (size_t)n * HIN * HIN * CI;

    if constexpr (DIRECT) {
#pragma unroll
        for (int ch = 0; ch < NCH; ++ch) {
#pragma unroll
            for (int kk = 0; kk < CC / 32; ++kk) {
                short8v a[2], b[NF];
#pragma unroll
                for (int mf = 0; mf < 2; ++mf) {
                    int co = coBase + wm * 32 + mf * 16 + l15;
                    a[mf] = *reinterpret_cast<const short8v*>(
                        Wp + ((size_t)ch * Co + co) * CC + kk * 32 + lq * 8);
                }
#pragma unroll
                for (int nf = 0; nf < NF; ++nf) {
                    b[nf] = *reinterpret_cast<const short8v*>(
                        Xn + ((size_t)((tr0 + prow[nf]) * STRIDE) * HIN +
                              (tc0 + pcol[nf]) * STRIDE) * CI + ch * CC + kk * 32 + lq * 8);
                }
#pragma unroll
                for (int mf = 0; mf < 2; ++mf)
#pragma unroll
                    for (int nf = 0; nf < NF; ++nf)
                        acc[mf][nf] = __builtin_amdgcn_mfma_f32_16x16x32_bf16(
                            a[mf], b[nf], acc[mf][nf], 0, 0, 0);
            }
        }
    } else if constexpr (CC == 32) {
        short8v wl[RSRS][2];   // chunk weights in regs (72 VGPR)

        auto wload = [&](int ch) {
#pragma unroll
            for (int j = 0; j < RSRS; ++j)
#pragma unroll
                for (int mf = 0; mf < 2; ++mf) {
                    int co = coBase + wm * 32 + mf * 16 + l15;
                    wl[j][mf] = *reinterpret_cast<const short8v*>(
                        Wp + (((size_t)(ch * RSRS + j) * Co + co) * CC + lq * 8));
                }
        };

        auto stage = [&](int ch, bf* buf) {
#pragma unroll
            for (int i = 0; i < NITER; ++i) {
                int g = tid + i * 256;
                int ir = g / (IN_COLS * NG);
                int rem = g - ir * (IN_COLS * NG);
                int ic = rem / NG;
                int gc = rem - ic * NG;
                int in_r = tr0 * STRIDE - PAD + ir;
                int in_c = tc0 * STRIDE - PAD + ic;
                int gsrc = gc ^ ((ic >> KSH) & (NG - 1));   // involution
                const bf* src = zpage;
                if (g < TG && (unsigned)in_r < (unsigned)HIN && (unsigned)in_c < (unsigned)HIN)
                    src = Xn + ((size_t)in_r * HIN + in_c) * CI + ch * CC + gsrc * 8;
                gload16(src, &buf[(size_t)g * 8]);   // branchless, all lanes issue
            }
        };

        auto compute = [&](const bf* buf) {
#pragma unroll
            for (int j = 0; j < RSRS; ++j) {
                const int dh = j / RS;
                const int dw = j % RS;
                short8v b[NF];
#pragma unroll
                for (int nf = 0; nf < NF; ++nf) {
                    int ir = prow[nf] * STRIDE + dh;
                    int ic = pcol[nf] * STRIDE + dw;
                    int gk = lq ^ ((ic >> KSH) & (NG - 1));
                    b[nf] = *reinterpret_cast<const short8v*>(
                        &buf[((ir * IN_COLS + ic) * NG + gk) * 8]);
                }
#pragma unroll
                for (int mf = 0; mf < 2; ++mf)
#pragma unroll
                    for (int nf = 0; nf < NF; ++nf)
                        acc[mf][nf] = __builtin_amdgcn_mfma_f32_16x16x32_bf16(
                            wl[j][mf], b[nf], acc[mf][nf], 0, 0, 0);
            }
        };

        wload(0);
        __builtin_amdgcn_sched_barrier(0);   // weights issued BEFORE staging
        stage(0, sX);
        __syncthreads();
#pragma unroll 1
        for (int ch = 0; ch < NCH; ++ch) {
            const bf* cur = sX + (size_t)(PIPE ? (ch & 1) : 0) * BUFE;
            bf* nxt = sX + (size_t)(PIPE ? ((ch + 1) & 1) : 0) * BUFE;
            if (ch + 1 < NCH) stage(ch + 1, nxt);      // in flight through compute
            __builtin_amdgcn_sched_barrier(0);
            compute(cur);
            if (ch + 1 < NCH) {
                wload(ch + 1);                          // next chunk weights
                __syncthreads();                        // drain lands post-compute
            }
        }
    } else {
        // CC==8 seed conv: single chunk, K padded 72->96, per-lane tap j = kt*4+lq
        stage_seed:;
#pragma unroll
        for (int i = 0; i < NITER; ++i) {
            int g = tid + i * 256;
            int ir = g / (IN_COLS * NG);
            int rem = g - ir * (IN_COLS * NG);
            int ic = rem / NG;
            int in_r = tr0 - PAD + ir;
            int in_c = tc0 - PAD + ic;
            const bf* src = zpage;
            if (g < TG && (unsigned)in_r < (unsigned)HIN && (unsigned)in_c < (unsigned)HIN)
                src = Xn + ((size_t)in_r * HIN + in_c) * CI;
            gload16(src, &sX[(size_t)g * 8]);
        }
        __syncthreads();
#pragma unroll
        for (int kt = 0; kt < 3; ++kt) {
            int j = kt * 4 + lq;
            int jj = (j < 9) ? j : 0;
            int dh = jj / 3, dw = jj % 3;
            short8v a[2], b[NF];
#pragma unroll
            for (int mf = 0; mf < 2; ++mf) {
                int co = coBase + wm * 32 + mf * 16 + l15;
                a[mf] = *reinterpret_cast<const short8v*>(Wp + ((size_t)j * Co + co) * 8);
            }
#pragma unroll
            for (int nf = 0; nf < NF; ++nf) {
                int ir = prow[nf] + dh;
                int ic = pcol[nf] + dw;
                b[nf] = *reinterpret_cast<const short8v*>(&sX[(ir * IN_COLS + ic) * 8]);
            }
#pragma unroll
            for (int mf = 0; mf < 2; ++mf)
#pragma unroll
                for (int nf = 0; nf < NF; ++nf)
                    acc[mf][nf] = __builtin_amdgcn_mfma_f32_16x16x32_bf16(
                        a[mf], b[nf], acc[mf][nf], 0, 0, 0);
        }
    }

    // epilogue: bias (+res, relu, mask), store NHWC bf16
#pragma unroll
    for (int mf = 0; mf < 2; ++mf) {
        int co0 = coBase + wm * 32 + mf * 16 + lq * 4;
        float4 b4 = *reinterpret_cast<const float4*>(bias + co0);
        float bb[4] = {b4.x, b4.y, b4.z, b4.w};
#pragma unroll
        for (int nf = 0; nf < NF; ++nf) {
            size_t off = ((size_t)n * W * W + (size_t)(tr0 + prow[nf]) * W + tc0 + pcol[nf]) * Co + co0;
            float v[4];
#pragma unroll
            for (int i = 0; i < 4; ++i) v[i] = acc[mf][nf][i] + bb[i];
            if constexpr (CMB >= 1) {
                u32x2 r2 = *reinterpret_cast<const u32x2*>(res + off);
                bf rr[4] = {(bf)(r2[0] & 0xffff), (bf)(r2[0] >> 16),
                            (bf)(r2[1] & 0xffff), (bf)(r2[1] >> 16)};
#pragma unroll
                for (int i = 0; i < 4; ++i) v[i] = fmaxf(v[i] + bf2f(rr[i]), 0.f);
            }
            if constexpr (RELU) {
#pragma unroll
                for (int i = 0; i < 4; ++i) v[i] = fmaxf(v[i], 0.f);
            }
            unsigned lo = (unsigned)f2bf(v[0]) | ((unsigned)f2bf(v[1]) << 16);
            unsigned hi = (unsigned)f2bf(v[2]) | ((unsigned)f2bf(v[3]) << 16);
            u32x2 o2 = {lo, hi};
            *reinterpret_cast<u32x2*>(Y + off) = o2;
        }
    }
}

// ---------------------------------------------------------------------------
// Fused repack (x8 vectorized): OIHW fp32 -> [chunk][tap][co][ci] bf16.
#define NSEG 34
struct Seg {
    const float* src;
    bf* dst;
    int Co, Ci, RSRS, CC, JPAD, blk0;
};
struct SegArgs {
    Seg s[NSEG];
};
__global__ void repack_all(SegArgs A) {
    int b = blockIdx.x;
    int lo = 0;
#pragma unroll 1
    for (int i = 1; i < NSEG; ++i)
        if (A.s[i].blk0 <= b) lo = i;
    Seg sg = A.s[lo];
    int NCH_ = (sg.Ci + sg.CC - 1) / sg.CC;
    size_t total8 = ((size_t)NCH_ * sg.JPAD * sg.Co * sg.CC) >> 3;
    size_t i8 = (size_t)(b - sg.blk0) * 256 + threadIdx.x;
    if (i8 >= total8) return;
    size_t e = i8 * 8;
    int cw = (int)(e % sg.CC);
    int co = (int)((e / sg.CC) % sg.Co);
    int j = (int)((e / ((size_t)sg.CC * sg.Co)) % sg.JPAD);
    int ch = (int)(e / ((size_t)sg.CC * sg.Co * sg.JPAD));
    bf tmp[8];
#pragma unroll
    for (int k = 0; k < 8; ++k) {
        int ci = ch * sg.CC + cw + k;
        float v = 0.f;
        if (ci < sg.Ci && j < sg.RSRS) v = sg.src[((size_t)co * sg.Ci + ci) * sg.RSRS + j];
        tmp[k] = f2bf(v);
    }
    u32x4 o;
#pragma unroll
    for (int k = 0; k < 4; ++k) o[k] = (unsigned)tmp[2 * k] | ((unsigned)tmp[2 * k + 1] << 16);
    *reinterpret_cast<u32x4*>(sg.dst + e) = o;
}

// NCHW fp32 [128,3,64,64] -> NHWC bf16 [128,64,64,8] (channels zero-padded)
__global__ void cvt_in(const float* __restrict__ in, bf* __restrict__ out) {
    size_t idx = (size_t)blockIdx.x * 256 + threadIdx.x;
    int c = (int)(idx & 7);
    size_t pix = idx >> 3;
    int w = (int)(pix & 63);
    int h = (int)((pix >> 6) & 63);
    int n = (int)(pix >> 12);
    float v = 0.f;
    if (c < 3) v = in[(((size_t)n * 3 + c) * 64 + h) * 64 + w];
    out[idx] = f2bf(v);
}

__global__ void zero_k(bf* p) {
    u32x4 z = {0, 0, 0, 0};
    *reinterpret_cast<u32x4*>(p + (size_t)threadIdx.x * 8) = z;
}

// [NB,256px,256ch] bf16 -> mean over px -> [NB,256] f32.
__global__ void pool_k(const bf* __restrict__ X, float* __restrict__ pooled) {
    __shared__ float red[8][256];
    int n = blockIdx.x;
    int g = threadIdx.x & 31;
    int slice = threadIdx.x >> 5;
    float acc[8] = {};
    for (int p = slice * 32; p < slice * 32 + 32; ++p) {
        u32x4 v = *reinterpret_cast<const u32x4*>(X + ((size_t)n * 256 + p) * 256 + g * 8);
#pragma unroll
        for (int i = 0; i < 4; ++i) {
            acc[2 * i] += bf2f((bf)(v[i] & 0xffff));
            acc[2 * i + 1] += bf2f((bf)(v[i] >> 16));
        }
    }
#pragma unroll
    for (int i = 0; i < 8; ++i) red[slice][g * 8 + i] = acc[i];
    __syncthreads();
    if (slice == 0) {
#pragma unroll
        for (int i = 0; i < 8; ++i) {
            float s = 0.f;
#pragma unroll
            for (int ss = 0; ss < 8; ++ss) s += red[ss][g * 8 + i];
            pooled[n * 256 + g * 8 + i] = s * (1.f / 256.f);
        }
    }
}

__global__ void fc_k(const float* __restrict__ pooled, const float* __restrict__ fw,
                     const float* __restrict__ fb, float* __restrict__ out) {
    __shared__ float sp[256];
    int n = blockIdx.x;
    sp[threadIdx.x] = pooled[n * 256 + threadIdx.x];
    __syncthreads();
    for (int o = threadIdx.x; o < 1000; o += 256) {
        float acc = fb[o];
        for (int k = 0; k < 256; ++k) acc += sp[k] * fw[(size_t)o * 256 + k];
        out[(size_t)n * 1000 + o] = acc;
    }
}

// ---------------------------------------------------------------------------
// Stride-2 ops (ds + conv1) use TH2xTW2 tiles; stride-1 identity use TH1xTW1.
template <int CIN, int COUT, int S, int TH1, int TW1, int TH2, int TW2, int W>
static void run_group(hipStream_t st, bf* X, bf* H, bf* OUT, const bf* zp,
                      bf* wp_ds, const float* ds_b, bf* wp_w1, const float* b1,
                      bf* wp_w2, const float* b2, bf* const* wp_rw1, const float* rb1,
                      bf* const* wp_rw2, const float* rb2, const float* probs_c,
                      int kbase, int NB) {
    dim3 grid1((W / TH1) * (W / TW1), COUT / 64, NB);
    dim3 grid2((W / TH2) * (W / TW2), COUT / 64, NB);
    conv_mfma<CIN, 64, 1, S, false, 0, TH2, TW2, W><<<grid2, 256, 0, st>>>(
        X, wp_ds, ds_b, OUT, nullptr, nullptr, zp, -1, COUT);
    conv_mfma<CIN, 32, 3, S, true, 0, TH2, TW2, W><<<grid2, 256, 0, st>>>(
        X, wp_w1, b1, H, nullptr, probs_c, zp, kbase, COUT);
    conv_mfma<COUT, 32, 3, 1, false, 2, TH1, TW1, W><<<grid1, 256, 0, st>>>(
        H, wp_w2, b2, OUT, OUT, probs_c, zp, kbase, COUT);
    for (int j = 0; j < 4; ++j) {
        conv_mfma<COUT, 32, 3, 1, true, 0, TH1, TW1, W><<<grid1, 256, 0, st>>>(
            OUT, wp_rw1[j], rb1 + j * COUT, H, nullptr, probs_c, zp, kbase + 1 + j, COUT);
        conv_mfma<COUT, 32, 3, 1, false, 2, TH1, TW1, W><<<grid1, 256, 0, st>>>(
            H, wp_rw2[j], rb2 + j * COUT, OUT, OUT, probs_c, zp, kbase + 1 + j, COUT);
    }
}

extern "C" void kernel_launch(void* const* d_in, const int* in_sizes, int n_in,
                              void* d_out, int out_size, void* d_ws, size_t ws_size,
                              hipStream_t stream) {
    (void)in_sizes; (void)n_in; (void)out_size;
    const float* input = (const float*)d_in[0];
    const float* probs = (const float*)d_in[1];
    const float* seed_w = (const float*)d_in[2];
    const float* seed_b = (const float*)d_in[3];
    const float* fc_w = (const float*)d_in[34];
    const float* fc_b = (const float*)d_in[35];

    char* pw = (char*)d_ws;
    auto alloc = [&](size_t bytes) -> void* {
        void* r = (void*)pw;
        pw += ((bytes + 255) & ~(size_t)255);
        return r;
    };

    bf* xin = (bf*)alloc(128ull * 64 * 64 * 8 * 2);
    float* pooled = (float*)alloc(128 * 256 * 4);
    bf* zpage = (bf*)alloc(256);   // zero-page for OOB / pad loads

    SegArgs sa;
    int nseg = 0;
    int blkAcc = 0;
    auto pack = [&](const float* w, int Co_, int Ci_, int RSRS_, int CC_, int JPAD_) -> bf* {
        int NCH_ = (Ci_ + CC_ - 1) / CC_;
        size_t total = (size_t)NCH_ * JPAD_ * Co_ * CC_;
        bf* wp = (bf*)alloc(total * 2);
        sa.s[nseg] = {w, wp, Co_, Ci_, RSRS_, CC_, JPAD_, blkAcc};
        blkAcc += (int)(((total >> 3) + 255) / 256);
        ++nseg;
        return wp;
    };

    zero_k<<<dim3(1), 16, 0, stream>>>(zpage);
    cvt_in<<<dim3(16384), 256, 0, stream>>>(input, xin);

    bf* wpSeed = pack(seed_w, 64, 3, 9, 8, 12);
    const int cis[3] = {64, 64, 128};
    const int cos[3] = {64, 128, 256};
    bf* wp_ds[3];
    bf* wp_w1[3];
    bf* wp_w2[3];
    bf* wp_rw1[3][4];
    bf* wp_rw2[3][4];
    const float *ds_b[3], *b1[3], *b2[3], *rb1[3], *rb2[3];
    for (int g = 0; g < 3; ++g) {
        int base = 4 + g * 10;
        const float* dsw = (const float*)d_in[base + 0];
        ds_b[g] = (const float*)d_in[base + 1];
        const float* w1 = (const float*)d_in[base + 2];
        b1[g] = (const float*)d_in[base + 3];
        const float* w2 = (const float*)d_in[base + 4];
        b2[g] = (const float*)d_in[base + 5];
        const float* rw1 = (const float*)d_in[base + 6];
        rb1[g] = (const float*)d_in[base + 7];
        const float* rw2 = (const float*)d_in[base + 8];
        rb2[g] = (const float*)d_in[base + 9];
        int Ci = cis[g], Co = cos[g];
        wp_ds[g] = pack(dsw, Co, Ci, 1, 64, 1);
        wp_w1[g] = pack(w1, Co, Ci, 9, 32, 9);
        wp_w2[g] = pack(w2, Co, Co, 9, 32, 9);
        for (int j = 0; j < 4; ++j) {
            wp_rw1[g][j] = pack(rw1 + (size_t)j * Co * Co * 9, Co, Co, 9, 32, 9);
            wp_rw2[g][j] = pack(rw2 + (size_t)j * Co * Co * 9, Co, Co, 9, 32, 9);
        }
    }
    for (int i = nseg; i < NSEG; ++i) sa.s[i] = {nullptr, nullptr, 1, 1, 1, 1, 1, 0x7fffffff};
    repack_all<<<dim3(blkAcc), 256, 0, stream>>>(sa);

    // ---- batch chunking to fit workspace ----
    size_t used = (size_t)(pw - (char*)d_ws);
    size_t avail = (ws_size > used) ? (ws_size - used) : 0;
    const size_t PER_IMG = 64ull * 64 * 64 * 2;  // 512 KB
    int NB = 128;
    while (NB > 8 && (size_t)3 * NB * PER_IMG + 4096 > avail) NB >>= 1;

    bf* A = (bf*)alloc((size_t)NB * PER_IMG);
    bf* Bb = (bf*)alloc((size_t)NB * PER_IMG);
    bf* C = (bf*)alloc((size_t)NB * PER_IMG);

    for (int n0 = 0; n0 < 128; n0 += NB) {
        const float* pc = probs + (size_t)n0 * 15;
        // seed conv (+relu): [NB,64,64,8] -> [NB,64,64,64]
        conv_mfma<8, 8, 3, 1, true, 0, 8, 16, 64><<<dim3(32, 1, NB), 256, 0, stream>>>(
            xin + (size_t)n0 * 64 * 64 * 8, wpSeed, seed_b, A, nullptr, nullptr, zpage, -1, 64);

        run_group<64, 64, 1, 8, 16, 8, 16, 64>(stream, A, Bb, C, zpage,
                                               wp_ds[0], ds_b[0], wp_w1[0], b1[0],
                                               wp_w2[0], b2[0], wp_rw1[0], rb1[0],
                                               wp_rw2[0], rb2[0], pc, 0, NB);
        run_group<64, 128, 2, 8, 16, 8, 8, 32>(stream, C, Bb, A, zpage,
                                               wp_ds[1], ds_b[1], wp_w1[1], b1[1],
                                               wp_w2[1], b2[1], wp_rw1[1], rb1[1],
                                               wp_rw2[1], rb2[1], pc, 5, NB);
        run_group<128, 256, 2, 8, 16, 8, 8, 16>(stream, A, Bb, C, zpage,
                                                wp_ds[2], ds_b[2], wp_w1[2], b1[2],
                                                wp_w2[2], b2[2], wp_rw1[2], rb1[2],
                                                wp_rw2[2], rb2[2], pc, 10, NB);

        pool_k<<<dim3(NB), 256, 0, stream>>>(C, pooled + (size_t)n0 * 256);
    }

    fc_k<<<dim3(128), 256, 0, stream>>>(pooled, fc_w, fc_b, (float*)d_out);
}

// Round 10
// 2182.102 us; speedup vs baseline: 1.4188x; 1.4188x over previous
//
#include <hip/hip_runtime.h>

using bf = unsigned short;
typedef __attribute__((ext_vector_type(8))) short short8v;
typedef __attribute__((ext_vector_type(4))) float f32x4;
typedef __attribute__((ext_vector_type(4))) unsigned int u32x4;
typedef __attribute__((ext_vector_type(2))) unsigned int u32x2;

__device__ __forceinline__ float bf2f(bf u) { return __uint_as_float(((unsigned)u) << 16); }
__device__ __forceinline__ bf f2bf(float f) {
    unsigned x = __float_as_uint(f);
    x += 0x7fffu + ((x >> 16) & 1u);   // RNE
    return (bf)(x >> 16);
}

// async global->LDS, 16B/lane; LDS dest linear in lane id, global src per-lane.
__device__ __forceinline__ void gload16(const bf* g, bf* l) {
    __builtin_amdgcn_global_load_lds(
        (const __attribute__((address_space(1))) void*)g,
        (__attribute__((address_space(3))) void*)l, 16, 0, 0);
}

// ---------------------------------------------------------------------------
// Implicit-GEMM 3x3 conv, NHWC bf16, fp32 accum. 256 thr = 4 waves (2co x 2px),
// 2D 8x16 pixel tiles (128 px), acc[2][4]. Single-buffer LDS staging via
// global_load_lds, padded to full waves (OOB/pad lanes -> zero-page). XOR
// swizzle on global source granule == LDS read granule (same involution).
// DS:   fused 1x1 downsample = center tap of the staged halo -> second
//       accumulator set; masked images compute ONLY the ds part.
// SEED: stage NCHW fp32 input -> LDS bf16 inline (no separate cvt pass).
// CMB2: in-place residual combine y = relu(acc+bias+y); masked blocks return
//       with zero traffic (Y==res).
// ---------------------------------------------------------------------------
template <int CI, int CC, int STRIDE, bool SEED, bool DS, bool RELU, int CMB,
          int TH, int TW, int W>
__global__ __launch_bounds__(256, 3) void conv_mfma(
    const bf* __restrict__ X, const float* __restrict__ Xf,
    const bf* __restrict__ Wp, const bf* __restrict__ Wds,
    const float* __restrict__ bias, const float* __restrict__ dsb,
    bf* __restrict__ Y, bf* __restrict__ Yds,
    const bf* __restrict__ res, const float* __restrict__ probs,
    const bf* __restrict__ zpage, int kidx, int Co) {
    constexpr int IN_ROWS = (TH - 1) * STRIDE + 3;
    constexpr int IN_COLS = (TW - 1) * STRIDE + 3;
    constexpr int NG = CC / 8;
    constexpr int HIN = W * STRIDE;
    constexpr int NCH = CI / CC;
    constexpr int TG = IN_ROWS * IN_COLS * NG;
    constexpr int NITER = (TG + 255) / 256;
    constexpr int NF = (TH * TW) / 32;
    constexpr int TPR = W / TW;
    constexpr int KSH = (STRIDE == 2) ? 1 : 0;

    __shared__ bf sX[SEED ? TG * 8 : NITER * 256 * 8];

    const int tid = threadIdx.x;
    const int n = blockIdx.z;
    const int coBase = blockIdx.y << 6;
    const int bx = blockIdx.x;
    const int tr0 = (bx / TPR) * TH;
    const int tc0 = (bx % TPR) * TW;

    bool active = true;
    if (kidx >= 0) active = (probs[n * 15 + kidx] >= 0.5f);
    if (!active && !DS) return;   // conv1: H unused; conv2 (CMB2): Y==res correct.

    const int lane = tid & 63;
    const int wid = tid >> 6;
    const int l15 = lane & 15;
    const int lq = lane >> 4;
    const int wm = wid >> 1;
    const int wn = wid & 1;

    f32x4 acc[2][NF] = {};
    f32x4 accds[DS ? 2 : 1][DS ? NF : 1] = {};
    int prow[NF], pcol[NF];
#pragma unroll
    for (int nf = 0; nf < NF; ++nf) {
        int p = wn * (TH * TW / 2) + nf * 16 + l15;
        prow[nf] = p / TW;
        pcol[nf] = p % TW;
    }

    const bf* Xn = X + (size_t)n * HIN * HIN * CI;

    for (int ch = 0; ch < NCH; ++ch) {
        if (ch) __syncthreads();
        // ---- stage halo chunk -> LDS ----
        if constexpr (SEED) {
            // NCHW fp32 -> bf16 granules (8ch slot, 3 real) inline
            const float* Xfn = Xf + (size_t)n * 3 * HIN * HIN;   // per-image base
            if (tid < TG) {   // NG==1: granule == pixel; TG=180 < 256
                int ir = tid / IN_COLS;
                int ic = tid % IN_COLS;
                int in_r = tr0 - 1 + ir;
                int in_c = tc0 - 1 + ic;
                u32x4 u = {0, 0, 0, 0};
                if ((unsigned)in_r < (unsigned)HIN && (unsigned)in_c < (unsigned)HIN) {
                    const float* p = Xfn + (size_t)in_r * HIN + in_c;
                    u[0] = (unsigned)f2bf(p[0]) | ((unsigned)f2bf(p[HIN * HIN]) << 16);
                    u[1] = (unsigned)f2bf(p[2 * HIN * HIN]);
                }
                *reinterpret_cast<u32x4*>(&sX[(size_t)tid * 8]) = u;
            }
        } else {
#pragma unroll
            for (int i = 0; i < NITER; ++i) {
                int g = tid + i * 256;
                int ir = g / (IN_COLS * NG);
                int rem = g - ir * (IN_COLS * NG);
                int ic = rem / NG;
                int gc = rem - ic * NG;
                int in_r = tr0 * STRIDE - 1 + ir;
                int in_c = tc0 * STRIDE - 1 + ic;
                int gsrc = gc ^ ((ic >> KSH) & (NG - 1));   // involution
                const bf* src = zpage;
                if (g < TG && (unsigned)in_r < (unsigned)HIN && (unsigned)in_c < (unsigned)HIN)
                    src = Xn + ((size_t)in_r * HIN + in_c) * CI + ch * CC + gsrc * 8;
                gload16(src, &sX[(size_t)g * 8]);   // branchless full-wave issue
            }
        }
        __syncthreads();

        // ---- compute ----
        if constexpr (SEED) {
            // CC==8: K padded 72->96, per-lane tap j = kt*4 + lq
#pragma unroll
            for (int kt = 0; kt < 3; ++kt) {
                int j = kt * 4 + lq;
                int jj = (j < 9) ? j : 0;
                int dh = jj / 3, dw = jj % 3;
                short8v a[2], b[NF];
#pragma unroll
                for (int mf = 0; mf < 2; ++mf) {
                    int co = coBase + wm * 32 + mf * 16 + l15;
                    a[mf] = *reinterpret_cast<const short8v*>(Wp + ((size_t)j * Co + co) * 8);
                }
#pragma unroll
                for (int nf = 0; nf < NF; ++nf) {
                    int ir = prow[nf] + dh;
                    int ic = pcol[nf] + dw;
                    b[nf] = *reinterpret_cast<const short8v*>(&sX[(ir * IN_COLS + ic) * 8]);
                }
#pragma unroll
                for (int mf = 0; mf < 2; ++mf)
#pragma unroll
                    for (int nf = 0; nf < NF; ++nf)
                        acc[mf][nf] = __builtin_amdgcn_mfma_f32_16x16x32_bf16(
                            a[mf], b[nf], acc[mf][nf], 0, 0, 0);
            }
        } else if (active) {
#pragma unroll
            for (int j = 0; j < 9; ++j) {
                const int dh = j / 3;
                const int dw = j % 3;
#pragma unroll
                for (int kk = 0; kk < CC / 32; ++kk) {
                    short8v a[2], b[NF];
#pragma unroll
                    for (int mf = 0; mf < 2; ++mf) {
                        int co = coBase + wm * 32 + mf * 16 + l15;
                        a[mf] = *reinterpret_cast<const short8v*>(
                            Wp + (((size_t)(ch * 9 + j) * Co + co) * CC + kk * 32 + lq * 8));
                    }
#pragma unroll
                    for (int nf = 0; nf < NF; ++nf) {
                        int ir = prow[nf] * STRIDE + dh;
                        int ic = pcol[nf] * STRIDE + dw;
                        int gk = (kk * 4 + lq) ^ ((ic >> KSH) & (NG - 1));
                        b[nf] = *reinterpret_cast<const short8v*>(
                            &sX[((ir * IN_COLS + ic) * NG + gk) * 8]);
                    }
#pragma unroll
                    for (int mf = 0; mf < 2; ++mf)
#pragma unroll
                        for (int nf = 0; nf < NF; ++nf)
                            acc[mf][nf] = __builtin_amdgcn_mfma_f32_16x16x32_bf16(
                                a[mf], b[nf], acc[mf][nf], 0, 0, 0);
                    if constexpr (DS) {
                        if (j == 4) {   // center tap == the 1x1 downsample input
                            short8v ads[2];
#pragma unroll
                            for (int mf = 0; mf < 2; ++mf) {
                                int co = coBase + wm * 32 + mf * 16 + l15;
                                ads[mf] = *reinterpret_cast<const short8v*>(
                                    Wds + ((size_t)ch * Co + co) * CC + kk * 32 + lq * 8);
                            }
#pragma unroll
                            for (int mf = 0; mf < 2; ++mf)
#pragma unroll
                                for (int nf = 0; nf < NF; ++nf)
                                    accds[mf][nf] = __builtin_amdgcn_mfma_f32_16x16x32_bf16(
                                        ads[mf], b[nf], accds[mf][nf], 0, 0, 0);
                        }
                    }
                }
            }
        } else if constexpr (DS) {
            // masked: downsample only (center tap)
#pragma unroll
            for (int kk = 0; kk < CC / 32; ++kk) {
                short8v ads[2], b[NF];
#pragma unroll
                for (int mf = 0; mf < 2; ++mf) {
                    int co = coBase + wm * 32 + mf * 16 + l15;
                    ads[mf] = *reinterpret_cast<const short8v*>(
                        Wds + ((size_t)ch * Co + co) * CC + kk * 32 + lq * 8);
                }
#pragma unroll
                for (int nf = 0; nf < NF; ++nf) {
                    int ir = prow[nf] * STRIDE + 1;
                    int ic = pcol[nf] * STRIDE + 1;
                    int gk = (kk * 4 + lq) ^ ((ic >> KSH) & (NG - 1));
                    b[nf] = *reinterpret_cast<const short8v*>(
                        &sX[((ir * IN_COLS + ic) * NG + gk) * 8]);
                }
#pragma unroll
                for (int mf = 0; mf < 2; ++mf)
#pragma unroll
                    for (int nf = 0; nf < NF; ++nf)
                        accds[mf][nf] = __builtin_amdgcn_mfma_f32_16x16x32_bf16(
                            ads[mf], b[nf], accds[mf][nf], 0, 0, 0);
            }
        }
    }

    // ---- epilogue ----
#pragma unroll
    for (int mf = 0; mf < 2; ++mf) {
        int co0 = coBase + wm * 32 + mf * 16 + lq * 4;
#pragma unroll
        for (int nf = 0; nf < NF; ++nf) {
            size_t off = ((size_t)n * W * W + (size_t)(tr0 + prow[nf]) * W + tc0 + pcol[nf]) * Co + co0;
            if constexpr (DS) {   // downsample output: always
                float4 d4 = *reinterpret_cast<const float4*>(dsb + co0);
                float v[4];
#pragma unroll
                for (int i = 0; i < 4; ++i)
                    v[i] = accds[mf][nf][i] + ((const float*)&d4)[i];
                unsigned lo = (unsigned)f2bf(v[0]) | ((unsigned)f2bf(v[1]) << 16);
                unsigned hi = (unsigned)f2bf(v[2]) | ((unsigned)f2bf(v[3]) << 16);
                u32x2 o2 = {lo, hi};
                *reinterpret_cast<u32x2*>(Yds + off) = o2;
            }
            if (active) {
                float4 b4 = *reinterpret_cast<const float4*>(bias + co0);
                float v[4];
#pragma unroll
                for (int i = 0; i < 4; ++i) v[i] = acc[mf][nf][i] + ((const float*)&b4)[i];
                if constexpr (CMB >= 1) {
                    u32x2 r2 = *reinterpret_cast<const u32x2*>(res + off);
                    bf rr[4] = {(bf)(r2[0] & 0xffff), (bf)(r2[0] >> 16),
                                (bf)(r2[1] & 0xffff), (bf)(r2[1] >> 16)};
#pragma unroll
                    for (int i = 0; i < 4; ++i) v[i] = fmaxf(v[i] + bf2f(rr[i]), 0.f);
                }
                if constexpr (RELU) {
#pragma unroll
                    for (int i = 0; i < 4; ++i) v[i] = fmaxf(v[i], 0.f);
                }
                unsigned lo = (unsigned)f2bf(v[0]) | ((unsigned)f2bf(v[1]) << 16);
                unsigned hi = (unsigned)f2bf(v[2]) | ((unsigned)f2bf(v[3]) << 16);
                u32x2 o2 = {lo, hi};
                *reinterpret_cast<u32x2*>(Y + off) = o2;
            }
        }
    }
}

// ---------------------------------------------------------------------------
// Fused repack (x8 vectorized): OIHW fp32 -> [chunk][tap][co][ci] bf16.
#define NSEG 34
struct Seg {
    const float* src;
    bf* dst;
    int Co, Ci, RSRS, CC, JPAD, blk0;
};
struct SegArgs {
    Seg s[NSEG];
};
__global__ void repack_all(SegArgs A) {
    int b = blockIdx.x;
    int lo = 0;
#pragma unroll 1
    for (int i = 1; i < NSEG; ++i)
        if (A.s[i].blk0 <= b) lo = i;
    Seg sg = A.s[lo];
    int NCH_ = (sg.Ci + sg.CC - 1) / sg.CC;
    size_t total8 = ((size_t)NCH_ * sg.JPAD * sg.Co * sg.CC) >> 3;
    size_t i8 = (size_t)(b - sg.blk0) * 256 + threadIdx.x;
    if (i8 >= total8) return;
    size_t e = i8 * 8;
    int cw = (int)(e % sg.CC);
    int co = (int)((e / sg.CC) % sg.Co);
    int j = (int)((e / ((size_t)sg.CC * sg.Co)) % sg.JPAD);
    int ch = (int)(e / ((size_t)sg.CC * sg.Co * sg.JPAD));
    bf tmp[8];
#pragma unroll
    for (int k = 0; k < 8; ++k) {
        int ci = ch * sg.CC + cw + k;
        float v = 0.f;
        if (ci < sg.Ci && j < sg.RSRS) v = sg.src[((size_t)co * sg.Ci + ci) * sg.RSRS + j];
        tmp[k] = f2bf(v);
    }
    u32x4 o;
#pragma unroll
    for (int k = 0; k < 4; ++k) o[k] = (unsigned)tmp[2 * k] | ((unsigned)tmp[2 * k + 1] << 16);
    *reinterpret_cast<u32x4*>(sg.dst + e) = o;
}

__global__ void zero_k(bf* p) {
    u32x4 z = {0, 0, 0, 0};
    *reinterpret_cast<u32x4*>(p + (size_t)threadIdx.x * 8) = z;
}

// Fused pool+fc: per image, mean over 256 px -> [256] -> fc 1000 outs (fp32).
__global__ void poolfc_k(const bf* __restrict__ X, const float* __restrict__ fw,
                         const float* __restrict__ fb, float* __restrict__ out) {
    __shared__ float red[8][256];
    __shared__ float sp[256];
    int n = blockIdx.x;
    int g = threadIdx.x & 31;
    int slice = threadIdx.x >> 5;
    float acc[8] = {};
    for (int p = slice * 32; p < slice * 32 + 32; ++p) {
        u32x4 v = *reinterpret_cast<const u32x4*>(X + ((size_t)n * 256 + p) * 256 + g * 8);
#pragma unroll
        for (int i = 0; i < 4; ++i) {
            acc[2 * i] += bf2f((bf)(v[i] & 0xffff));
            acc[2 * i + 1] += bf2f((bf)(v[i] >> 16));
        }
    }
#pragma unroll
    for (int i = 0; i < 8; ++i) red[slice][g * 8 + i] = acc[i];
    __syncthreads();
    if (slice == 0) {
#pragma unroll
        for (int i = 0; i < 8; ++i) {
            float s = 0.f;
#pragma unroll
            for (int ss = 0; ss < 8; ++ss) s += red[ss][g * 8 + i];
            sp[g * 8 + i] = s * (1.f / 256.f);
        }
    }
    __syncthreads();
    for (int o = threadIdx.x; o < 1000; o += 256) {
        float a = fb[o];
        for (int k = 0; k < 256; ++k) a += sp[k] * fw[(size_t)o * 256 + k];
        out[(size_t)n * 1000 + o] = a;
    }
}

// ---------------------------------------------------------------------------
// Group: fused(ds+conv1) -> conv2(in-place combine) -> 4x [conv1 -> conv2].
template <int CIN, int COUT, int S, int CC1, int W>
static void run_group(hipStream_t st, bf* X, bf* H, bf* OUT, const bf* zp,
                      bf* wp_ds, const float* ds_b, bf* wp_w1, const float* b1,
                      bf* wp_w2, const float* b2, bf* const* wp_rw1, const float* rb1,
                      bf* const* wp_rw2, const float* rb2, const float* probs_c,
                      int kbase, int NB) {
    dim3 grid((W / 8) * (W / 16), COUT / 64, NB);
    // fused: OUT = ds(X); H = relu(conv1(X)) [H skipped when masked]
    conv_mfma<CIN, CC1, S, false, true, true, 0, 8, 16, W><<<grid, 256, 0, st>>>(
        X, nullptr, wp_w1, wp_ds, b1, ds_b, H, OUT, nullptr, probs_c, zp, kbase, COUT);
    conv_mfma<COUT, 64, 1, false, false, false, 2, 8, 16, W><<<grid, 256, 0, st>>>(
        H, nullptr, wp_w2, nullptr, b2, nullptr, OUT, nullptr, OUT, probs_c, zp, kbase, COUT);
    for (int j = 0; j < 4; ++j) {
        conv_mfma<COUT, 64, 1, false, false, true, 0, 8, 16, W><<<grid, 256, 0, st>>>(
            OUT, nullptr, wp_rw1[j], nullptr, rb1 + j * COUT, nullptr, H, nullptr,
            nullptr, probs_c, zp, kbase + 1 + j, COUT);
        conv_mfma<COUT, 64, 1, false, false, false, 2, 8, 16, W><<<grid, 256, 0, st>>>(
            H, nullptr, wp_rw2[j], nullptr, rb2 + j * COUT, nullptr, OUT, nullptr,
            OUT, probs_c, zp, kbase + 1 + j, COUT);
    }
}

extern "C" void kernel_launch(void* const* d_in, const int* in_sizes, int n_in,
                              void* d_out, int out_size, void* d_ws, size_t ws_size,
                              hipStream_t stream) {
    (void)in_sizes; (void)n_in; (void)out_size;
    const float* input = (const float*)d_in[0];
    const float* probs = (const float*)d_in[1];
    const float* seed_w = (const float*)d_in[2];
    const float* seed_b = (const float*)d_in[3];
    const float* fc_w = (const float*)d_in[34];
    const float* fc_b = (const float*)d_in[35];

    char* pw = (char*)d_ws;
    auto alloc = [&](size_t bytes) -> void* {
        void* r = (void*)pw;
        pw += ((bytes + 255) & ~(size_t)255);
        return r;
    };

    bf* zpage = (bf*)alloc(256);

    SegArgs sa;
    int nseg = 0;
    int blkAcc = 0;
    auto pack = [&](const float* w, int Co_, int Ci_, int RSRS_, int CC_, int JPAD_) -> bf* {
        int NCH_ = (Ci_ + CC_ - 1) / CC_;
        size_t total = (size_t)NCH_ * JPAD_ * Co_ * CC_;
        bf* wp = (bf*)alloc(total * 2);
        sa.s[nseg] = {w, wp, Co_, Ci_, RSRS_, CC_, JPAD_, blkAcc};
        blkAcc += (int)(((total >> 3) + 255) / 256);
        ++nseg;
        return wp;
    };

    zero_k<<<dim3(1), 16, 0, stream>>>(zpage);

    bf* wpSeed = pack(seed_w, 64, 3, 9, 8, 12);
    const int cis[3] = {64, 64, 128};
    const int cos[3] = {64, 128, 256};
    const int cc1s[3] = {64, 32, 32};
    bf* wp_ds[3];
    bf* wp_w1[3];
    bf* wp_w2[3];
    bf* wp_rw1[3][4];
    bf* wp_rw2[3][4];
    const float *ds_b[3], *b1[3], *b2[3], *rb1[3], *rb2[3];
    for (int g = 0; g < 3; ++g) {
        int base = 4 + g * 10;
        const float* dsw = (const float*)d_in[base + 0];
        ds_b[g] = (const float*)d_in[base + 1];
        const float* w1 = (const float*)d_in[base + 2];
        b1[g] = (const float*)d_in[base + 3];
        const float* w2 = (const float*)d_in[base + 4];
        b2[g] = (const float*)d_in[base + 5];
        const float* rw1 = (const float*)d_in[base + 6];
        rb1[g] = (const float*)d_in[base + 7];
        const float* rw2 = (const float*)d_in[base + 8];
        rb2[g] = (const float*)d_in[base + 9];
        int Ci = cis[g], Co = cos[g];
        wp_ds[g] = pack(dsw, Co, Ci, 1, cc1s[g], 1);   // [ch][co][CC1] (RSRS=1)
        wp_w1[g] = pack(w1, Co, Ci, 9, cc1s[g], 9);
        wp_w2[g] = pack(w2, Co, Co, 9, 64, 9);
        for (int j = 0; j < 4; ++j) {
            wp_rw1[g][j] = pack(rw1 + (size_t)j * Co * Co * 9, Co, Co, 9, 64, 9);
            wp_rw2[g][j] = pack(rw2 + (size_t)j * Co * Co * 9, Co, Co, 9, 64, 9);
        }
    }
    for (int i = nseg; i < NSEG; ++i) sa.s[i] = {nullptr, nullptr, 1, 1, 1, 1, 1, 0x7fffffff};
    repack_all<<<dim3(blkAcc), 256, 0, stream>>>(sa);

    // ---- batch chunking to fit workspace ----
    size_t used = (size_t)(pw - (char*)d_ws);
    size_t avail = (ws_size > used) ? (ws_size - used) : 0;
    const size_t PER_IMG = 64ull * 64 * 64 * 2;  // 512 KB
    int NB = 128;
    while (NB > 8 && (size_t)3 * NB * PER_IMG + 4096 > avail) NB >>= 1;

    bf* A = (bf*)alloc((size_t)NB * PER_IMG);
    bf* Bb = (bf*)alloc((size_t)NB * PER_IMG);
    bf* C = (bf*)alloc((size_t)NB * PER_IMG);

    for (int n0 = 0; n0 < 128; n0 += NB) {
        const float* pc = probs + (size_t)n0 * 15;
        // seed conv (+relu) from fp32 NCHW directly: -> [NB,64,64,64] in A
        conv_mfma<8, 8, 1, true, false, true, 0, 8, 16, 64><<<dim3(32, 1, NB), 256, 0, stream>>>(
            nullptr, input + (size_t)n0 * 3 * 4096, wpSeed, nullptr, seed_b, nullptr,
            A, nullptr, nullptr, nullptr, zpage, -1, 64);

        run_group<64, 64, 1, 64, 64>(stream, A, Bb, C, zpage,
                                     wp_ds[0], ds_b[0], wp_w1[0], b1[0], wp_w2[0], b2[0],
                                     wp_rw1[0], rb1[0], wp_rw2[0], rb2[0], pc, 0, NB);
        run_group<64, 128, 2, 32, 32>(stream, C, Bb, A, zpage,
                                      wp_ds[1], ds_b[1], wp_w1[1], b1[1], wp_w2[1], b2[1],
                                      wp_rw1[1], rb1[1], wp_rw2[1], rb2[1], pc, 5, NB);
        run_group<128, 256, 2, 32, 16>(stream, A, Bb, C, zpage,
                                       wp_ds[2], ds_b[2], wp_w1[2], b1[2], wp_w2[2], b2[2],
                                       wp_rw1[2], rb1[2], wp_rw2[2], rb2[2], pc, 10, NB);

        poolfc_k<<<dim3(NB), 256, 0, stream>>>(C, fc_w, fc_b,
                                               (float*)d_out + (size_t)n0 * 1000);
    }
}